// Round 1
// baseline (300.105 us; speedup 1.0000x reference)
//
#include <hip/hip_runtime.h>

typedef __attribute__((ext_vector_type(8))) short bf16x8;
typedef __attribute__((ext_vector_type(4))) float f32x4;
typedef __attribute__((ext_vector_type(2))) unsigned short u16x2;
typedef __attribute__((ext_vector_type(4))) unsigned short u16x4;

static constexpr int kB = 2;
static constexpr int kT = 2048;
static constexpr int kC = 1024;
static constexpr int kH = 16;
static constexpr int kD = 64;

__device__ inline unsigned short f2bf(float f) {
    unsigned int u = __float_as_uint(f);
    u += 0x7FFFu + ((u >> 16) & 1u);
    return (unsigned short)(u >> 16);
}

// ---------------- f32 -> bf16 convert ----------------
__global__ __launch_bounds__(256) void cvt_bf16(const float* __restrict__ in,
                                                unsigned short* __restrict__ out, int n) {
    int i = (blockIdx.x * 256 + threadIdx.x) * 4;
    if (i >= n) return;
    float4 v = *(const float4*)(in + i);
    u16x4 o;
    o[0] = f2bf(v.x); o[1] = f2bf(v.y); o[2] = f2bf(v.z); o[3] = f2bf(v.w);
    *(u16x4*)(out + i) = o;
}

// ---------------- RoPE/xPos tables: (t, i) for i in [0,32) ----------------
__global__ __launch_bounds__(256) void rope_tables(float* __restrict__ ct,
                                                   float* __restrict__ st,
                                                   float* __restrict__ sc) {
    int idx = blockIdx.x * 256 + threadIdx.x;
    if (idx >= kT * 32) return;
    int t = idx >> 5, i = idx & 31;
    float half = 2.0f * (float)i;
    float inv_freq = powf(10000.0f, -half / 64.0f);
    float fr = (float)t * inv_freq;
    float sv = (half + 0.4f * 64.0f) / (1.4f * 64.0f);
    float p = ((float)t - 1024.0f) / 512.0f;
    ct[idx] = cosf(fr);
    st[idx] = sinf(fr);
    sc[idx] = powf(sv, p);
}

// ---------------- bf16 MFMA GEMM: C[M,N] = A[M,K] * Bm[N,K]^T, fp32 out ----------------
// tile 128x128, BK=64, 4 waves (2x2), each wave 64x64 (4x4 fragments of 16x16x32)
__global__ __launch_bounds__(256) void gemm_bt(const unsigned short* __restrict__ A,
                                               const unsigned short* __restrict__ Bm,
                                               float* __restrict__ Cm,
                                               int N, int K) {
    __shared__ unsigned short Al[128 * 64];
    __shared__ unsigned short Bl[128 * 64];
    char* ab = (char*)Al;
    char* bb = (char*)Bl;
    const int tid = threadIdx.x;
    const int l = tid & 63, w = tid >> 6;
    const int wr = w >> 1, wc = w & 1;
    const int tm = blockIdx.y * 128, tn = blockIdx.x * 128;
    const int r0 = tid >> 1;           // staging row 0..127
    const int ku0 = (tid & 1) * 4;     // staging 16B-unit base

    f32x4 zero4 = {0.0f, 0.0f, 0.0f, 0.0f};
    f32x4 acc[4][4];
#pragma unroll
    for (int m = 0; m < 4; m++)
#pragma unroll
        for (int n = 0; n < 4; n++) acc[m][n] = zero4;

    for (int kt = 0; kt < K; kt += 64) {
#pragma unroll
        for (int j = 0; j < 4; j++) {
            int ku = ku0 + j;
            bf16x8 va = *(const bf16x8*)(A + (size_t)(tm + r0) * K + kt + ku * 8);
            bf16x8 vb = *(const bf16x8*)(Bm + (size_t)(tn + r0) * K + kt + ku * 8);
            int swz = (r0 & 7) << 4;
            *(bf16x8*)(ab + r0 * 128 + ((ku * 16) ^ swz)) = va;
            *(bf16x8*)(bb + r0 * 128 + ((ku * 16) ^ swz)) = vb;
        }
        __syncthreads();
#pragma unroll
        for (int ks = 0; ks < 2; ks++) {
            bf16x8 af[4], bfr[4];
            int kbyte = ks * 64 + (l >> 4) * 16;
#pragma unroll
            for (int m = 0; m < 4; m++) {
                int row = wr * 64 + m * 16 + (l & 15);
                af[m] = *(const bf16x8*)(ab + row * 128 + (kbyte ^ ((row & 7) << 4)));
            }
#pragma unroll
            for (int n = 0; n < 4; n++) {
                int row = wc * 64 + n * 16 + (l & 15);
                bfr[n] = *(const bf16x8*)(bb + row * 128 + (kbyte ^ ((row & 7) << 4)));
            }
#pragma unroll
            for (int m = 0; m < 4; m++)
#pragma unroll
                for (int n = 0; n < 4; n++)
                    acc[m][n] = __builtin_amdgcn_mfma_f32_16x16x32_bf16(af[m], bfr[n], acc[m][n], 0, 0, 0);
        }
        __syncthreads();
    }
#pragma unroll
    for (int m = 0; m < 4; m++)
#pragma unroll
        for (int n = 0; n < 4; n++)
#pragma unroll
            for (int r = 0; r < 4; r++) {
                int row = tm + wr * 64 + m * 16 + (l >> 4) * 4 + r;
                int col = tn + wc * 64 + n * 16 + (l & 15);
                Cm[(size_t)row * N + col] = acc[m][n][r];
            }
}

// ---------------- RoPE for one of q/k: src fp32 (B*T, C) -> dst bf16 (B,H,T,D) ----------------
__global__ __launch_bounds__(256) void rope_one(const float* __restrict__ src,
                                                const float* __restrict__ ct,
                                                const float* __restrict__ st,
                                                const float* __restrict__ sc,
                                                unsigned short* __restrict__ dst, int is_q) {
    int idx = blockIdx.x * 256 + threadIdx.x;  // B*T*H*32
    int i = idx & 31;
    int h = (idx >> 5) & 15;
    int t = (idx >> 9) & 2047;
    int b = idx >> 20;
    const float* row = src + ((size_t)(b * kT + t)) * kC + h * kD + 2 * i;
    float x0 = row[0], x1 = row[1];
    int ti = t * 32 + i;
    float c = ct[ti], s = st[ti], sv = sc[ti];
    float cs, sn;
    if (is_q) { cs = c * sv; sn = s * sv; } else { cs = c / sv; sn = s / sv; }
    float o0 = x0 * cs - x1 * sn;
    float o1 = x1 * cs + x0 * sn;
    if (is_q) { o0 *= 0.125f; o1 *= 0.125f; }  // fold HEAD_DIM^-0.5 (exact pow2)
    size_t doff = (((size_t)(b * kH + h) * kT + t) * kD) + 2 * i;
    u16x2 o;
    o[0] = f2bf(o0); o[1] = f2bf(o1);
    *(u16x2*)(dst + doff) = o;
}

// ---------------- V: fp32 (B*T, C) -> bf16 transposed (B,H,D,T) ----------------
__global__ __launch_bounds__(256) void vt_from_f32(const float* __restrict__ vf,
                                                   unsigned short* __restrict__ vtb) {
    __shared__ unsigned short tile[64][72];
    int tt = blockIdx.x * 64;
    int bh = blockIdx.y;
    int b = bh >> 4, h = bh & 15;
    int r = threadIdx.x >> 2;
    int cu = (threadIdx.x & 3) * 16;
    const float* srow = vf + ((size_t)(b * kT) + tt + r) * kC + h * kD + cu;
#pragma unroll
    for (int j = 0; j < 16; j += 4) {
        float4 v = *(const float4*)(srow + j);
        tile[r][cu + j + 0] = f2bf(v.x);
        tile[r][cu + j + 1] = f2bf(v.y);
        tile[r][cu + j + 2] = f2bf(v.z);
        tile[r][cu + j + 3] = f2bf(v.w);
    }
    __syncthreads();
    int d = threadIdx.x >> 2;
    int tb = (threadIdx.x & 3) * 16;
    bf16x8 o0, o1;
#pragma unroll
    for (int e = 0; e < 8; e++) {
        o0[e] = (short)tile[tb + e][d];
        o1[e] = (short)tile[tb + 8 + e][d];
    }
    unsigned short* drow = vtb + ((size_t)bh * kD + d) * kT + tt + tb;
    *(bf16x8*)(drow) = o0;
    *(bf16x8*)(drow + 8) = o1;
}

// ---------------- retention attention: per (qt, bh), 64 q-rows, flash-style ----------------
__global__ __launch_bounds__(256) void retention_attn(const unsigned short* __restrict__ qb,
                                                      const unsigned short* __restrict__ kb,
                                                      const unsigned short* __restrict__ vtb,
                                                      float* __restrict__ y) {
    __shared__ unsigned short Kl[64 * 64];
    __shared__ unsigned short Vl[64 * 64];
    __shared__ unsigned short Pl[4 * 16 * 64];
    char* kbp = (char*)Kl;
    char* vbp = (char*)Vl;
    const int tid = threadIdx.x, l = tid & 63, w = tid >> 6;
    const int qt = blockIdx.x, bh = blockIdx.y;
    const int t0 = qt * 64;
    const int h = bh & 15;
    const float log2g = log2f(1.0f - exp2f(-5.0f - (float)h));

    // Q fragments held in registers (q already scaled by 0.125)
    bf16x8 aq[2];
    {
        const unsigned short* qrow = qb + (((size_t)bh * kT) + t0 + 16 * w + (l & 15)) * kD + (l >> 4) * 8;
        aq[0] = *(const bf16x8*)(qrow);
        aq[1] = *(const bf16x8*)(qrow + 32);
    }
    f32x4 zero4 = {0.0f, 0.0f, 0.0f, 0.0f};
    f32x4 accy[4];
#pragma unroll
    for (int j = 0; j < 4; j++) accy[j] = zero4;

    const int r0 = tid >> 2;          // staging row 0..63
    const int ku0 = (tid & 3) * 2;    // two 16B units per thread
    char* pw = ((char*)Pl) + w * 2048;  // wave-private 16x64 bf16 region

    for (int st = 0; st <= qt; ++st) {
        int s0 = st * 64;
#pragma unroll
        for (int j = 0; j < 2; j++) {
            int ku = ku0 + j;
            bf16x8 vk = *(const bf16x8*)(kb + (((size_t)bh * kT) + s0 + r0) * kD + ku * 8);
            bf16x8 vv = *(const bf16x8*)(vtb + (((size_t)bh * kD) + r0) * kT + s0 + ku * 8);
            int swz = (r0 & 7) << 4;
            *(bf16x8*)(kbp + r0 * 128 + ((ku * 16) ^ swz)) = vk;
            *(bf16x8*)(vbp + r0 * 128 + ((ku * 16) ^ swz)) = vv;
        }
        __syncthreads();

        // scores: S = Q * K^T (16 rows x 64 cols per wave)
        f32x4 sacc[4];
#pragma unroll
        for (int cb = 0; cb < 4; cb++) sacc[cb] = zero4;
#pragma unroll
        for (int ks = 0; ks < 2; ks++) {
            int kbyte = ks * 64 + (l >> 4) * 16;
#pragma unroll
            for (int cb = 0; cb < 4; cb++) {
                int row = cb * 16 + (l & 15);
                bf16x8 bk = *(const bf16x8*)(kbp + row * 128 + (kbyte ^ ((row & 7) << 4)));
                sacc[cb] = __builtin_amdgcn_mfma_f32_16x16x32_bf16(aq[ks], bk, sacc[cb], 0, 0, 0);
            }
        }
        // decay * causal, write P (bf16) to wave-private LDS
#pragma unroll
        for (int cb = 0; cb < 4; cb++) {
#pragma unroll
            for (int r = 0; r < 4; r++) {
                int prow = (l >> 4) * 4 + r;
                int rowt = t0 + 16 * w + prow;
                int sl = cb * 16 + (l & 15);
                int diff = rowt - (s0 + sl);
                float p = (diff >= 0) ? sacc[cb][r] * exp2f(log2g * (float)diff) : 0.0f;
                *(unsigned short*)(pw + prow * 128 + ((sl * 2) ^ ((prow & 7) << 4))) = f2bf(p);
            }
        }
        // PV: accumulate 16x64
#pragma unroll
        for (int ks = 0; ks < 2; ks++) {
            int kbyte = ks * 64 + (l >> 4) * 16;
            int prow = l & 15;
            bf16x8 ap = *(const bf16x8*)(pw + prow * 128 + (kbyte ^ ((prow & 7) << 4)));
#pragma unroll
            for (int jb = 0; jb < 4; jb++) {
                int drow = jb * 16 + (l & 15);
                bf16x8 bv = *(const bf16x8*)(vbp + drow * 128 + (kbyte ^ ((drow & 7) << 4)));
                accy[jb] = __builtin_amdgcn_mfma_f32_16x16x32_bf16(ap, bv, accy[jb], 0, 0, 0);
            }
        }
        __syncthreads();
    }
#pragma unroll
    for (int jb = 0; jb < 4; jb++)
#pragma unroll
        for (int r = 0; r < 4; r++) {
            int row = t0 + 16 * w + (l >> 4) * 4 + r;
            int col = jb * 16 + (l & 15);
            y[(((size_t)bh * kT) + row) * kD + col] = accy[jb][r];
        }
}

// ---------------- GroupNorm stats per (b,h): mean + rstd over D*T ----------------
__global__ __launch_bounds__(256) void gn_stats(const float* __restrict__ y,
                                                float* __restrict__ stats) {
    int bh = blockIdx.x;
    int tid = threadIdx.x;
    const float4* p = (const float4*)(y + (size_t)bh * (kT * kD));
    float s = 0.0f, s2 = 0.0f;
    for (int i = tid; i < (kT * kD) / 4; i += 256) {
        float4 v = p[i];
        s += v.x + v.y + v.z + v.w;
        s2 += v.x * v.x + v.y * v.y + v.z * v.z + v.w * v.w;
    }
#pragma unroll
    for (int o = 32; o > 0; o >>= 1) {
        s += __shfl_down(s, o);
        s2 += __shfl_down(s2, o);
    }
    __shared__ float red[8];
    if ((tid & 63) == 0) {
        red[(tid >> 6) * 2] = s;
        red[(tid >> 6) * 2 + 1] = s2;
    }
    __syncthreads();
    if (tid == 0) {
        float S = 0.0f, S2 = 0.0f;
#pragma unroll
        for (int i = 0; i < 4; i++) { S += red[2 * i]; S2 += red[2 * i + 1]; }
        const float inv = 1.0f / (float)(kT * kD);
        float mean = S * inv;
        float var = S2 * inv - mean * mean;
        stats[2 * bh] = mean;
        stats[2 * bh + 1] = rsqrtf(var + 1e-5f);
    }
}

// ---------------- z = bf16( silu(g) * ((y - mean)*rstd*gw + gb) ) ----------------
__global__ __launch_bounds__(256) void fuse_z(const float* __restrict__ g,
                                              const float* __restrict__ y,
                                              const float* __restrict__ stats,
                                              const float* __restrict__ gnw,
                                              const float* __restrict__ gnb,
                                              unsigned short* __restrict__ z) {
    int idx = blockIdx.x * 256 + threadIdx.x;  // (B*T*C)/4
    int row = idx >> 8;
    int c = (idx & 255) << 2;
    int b = row >> 11, t = row & 2047;
    int h = c >> 6, d = c & 63;
    int bh = b * kH + h;
    float4 gv = *(const float4*)(g + (size_t)row * kC + c);
    float4 yv = *(const float4*)(y + (((size_t)bh * kT) + t) * kD + d);
    float mean = stats[2 * bh], rstd = stats[2 * bh + 1];
    float4 wv = *(const float4*)(gnw + c);
    float4 bv = *(const float4*)(gnb + c);
    float s0 = gv.x / (1.0f + expf(-gv.x));
    float s1 = gv.y / (1.0f + expf(-gv.y));
    float s2 = gv.z / (1.0f + expf(-gv.z));
    float s3 = gv.w / (1.0f + expf(-gv.w));
    u16x4 o;
    o[0] = f2bf(s0 * ((yv.x - mean) * rstd * wv.x + bv.x));
    o[1] = f2bf(s1 * ((yv.y - mean) * rstd * wv.y + bv.y));
    o[2] = f2bf(s2 * ((yv.z - mean) * rstd * wv.z + bv.z));
    o[3] = f2bf(s3 * ((yv.w - mean) * rstd * wv.w + bv.w));
    *(u16x4*)(z + (size_t)row * kC + c) = o;
}

extern "C" void kernel_launch(void* const* d_in, const int* in_sizes, int n_in,
                              void* d_out, int out_size, void* d_ws, size_t ws_size,
                              hipStream_t stream) {
    const float* x = (const float*)d_in[0];
    const float* w_qkv = (const float*)d_in[1];
    const float* w_gated = (const float*)d_in[2];
    const float* w_proj = (const float*)d_in[3];
    const float* gnw = (const float*)d_in[4];
    const float* gnb = (const float*)d_in[5];
    float* out = (float*)d_out;
    char* ws = (char*)d_ws;

    unsigned short* xb     = (unsigned short*)(ws + 0);          //  8 MB: x bf16 (4096x1024)
    unsigned short* wqkvb  = (unsigned short*)(ws + 8388608);    //  6 MB: w_qkv bf16 (3072x1024)
    unsigned short* wgatedb= (unsigned short*)(ws + 14680064);   //  2 MB
    unsigned short* wprojb = (unsigned short*)(ws + 16777216);   //  2 MB
    unsigned short* qb     = (unsigned short*)(ws + 18874368);   //  8 MB: q bf16 (B,H,T,D), pre-scaled
    unsigned short* kbuf   = (unsigned short*)(ws + 27262976);   //  8 MB: k bf16 (B,H,T,D)
    unsigned short* vtb    = (unsigned short*)(ws + 35651584);   //  8 MB: v bf16 (B,H,D,T)
    unsigned short* zb     = (unsigned short*)(ws + 44040192);   //  8 MB: z bf16 (4096x1024)
    float* cosT  = (float*)(ws + 52428800);                      // 256 KB each
    float* sinT  = (float*)(ws + 52690944);
    float* sclT  = (float*)(ws + 52953088);
    float* stats = (float*)(ws + 53215232);                      // 32*2 floats
    float* tmpA  = (float*)(ws + 53215488);                      // 16 MB: q/k/v fp32 staging, then y
    float* tmpB  = (float*)(ws + 69992704);                      // 16 MB: g fp32

    cvt_bf16<<<4096, 256, 0, stream>>>(x, xb, kB * kT * kC);
    cvt_bf16<<<3072, 256, 0, stream>>>(w_qkv, wqkvb, 3 * kC * kC);
    cvt_bf16<<<1024, 256, 0, stream>>>(w_gated, wgatedb, kC * kC);
    cvt_bf16<<<1024, 256, 0, stream>>>(w_proj, wprojb, kC * kC);
    rope_tables<<<256, 256, 0, stream>>>(cosT, sinT, sclT);

    dim3 gg(kC / 128, (kB * kT) / 128);  // (8, 32)

    // q
    gemm_bt<<<gg, 256, 0, stream>>>(xb, wqkvb, tmpA, kC, kC);
    rope_one<<<8192, 256, 0, stream>>>(tmpA, cosT, sinT, sclT, qb, 1);
    // k
    gemm_bt<<<gg, 256, 0, stream>>>(xb, wqkvb + (size_t)kC * kC, tmpA, kC, kC);
    rope_one<<<8192, 256, 0, stream>>>(tmpA, cosT, sinT, sclT, kbuf, 0);
    // v (transposed to (B,H,D,T))
    gemm_bt<<<gg, 256, 0, stream>>>(xb, wqkvb + (size_t)2 * kC * kC, tmpA, kC, kC);
    vt_from_f32<<<dim3(kT / 64, kB * kH), 256, 0, stream>>>(tmpA, vtb);

    // retention attention -> y (fp32, (B,H,T,D)) into tmpA
    retention_attn<<<dim3(kT / 64, kB * kH), 256, 0, stream>>>(qb, kbuf, vtb, tmpA);

    gn_stats<<<kB * kH, 256, 0, stream>>>(tmpA, stats);

    // gated branch
    gemm_bt<<<gg, 256, 0, stream>>>(xb, wgatedb, tmpB, kC, kC);
    fuse_z<<<4096, 256, 0, stream>>>(tmpB, tmpA, stats, gnw, gnb, zb);

    // proj -> out
    gemm_bt<<<gg, 256, 0, stream>>>(zb, wprojb, out, kC, kC);
}

// Round 3
// 179.877 us; speedup vs baseline: 1.6684x; 1.6684x over previous
//
#include <hip/hip_runtime.h>

typedef __attribute__((ext_vector_type(8))) short bf16x8;
typedef __attribute__((ext_vector_type(4))) float f32x4;
typedef __attribute__((ext_vector_type(2))) unsigned short u16x2;
typedef __attribute__((ext_vector_type(4))) unsigned short u16x4;

static constexpr int kB = 2;
static constexpr int kT = 2048;
static constexpr int kC = 1024;
static constexpr int kH = 16;
static constexpr int kD = 64;

__device__ inline unsigned short f2bf(float f) {
    unsigned int u = __float_as_uint(f);
    u += 0x7FFFu + ((u >> 16) & 1u);
    return (unsigned short)(u >> 16);
}

#define GLDS16(g, s)                                                            \
    __builtin_amdgcn_global_load_lds(                                           \
        (const __attribute__((address_space(1))) unsigned int*)(g),             \
        (__attribute__((address_space(3))) unsigned int*)(s), 16, 0, 0)

// ---------------- f32 -> bf16 convert ----------------
__global__ __launch_bounds__(256) void cvt_bf16(const float* __restrict__ in,
                                                unsigned short* __restrict__ out, int n) {
    int i = (blockIdx.x * 256 + threadIdx.x) * 4;
    if (i >= n) return;
    float4 v = *(const float4*)(in + i);
    u16x4 o;
    o[0] = f2bf(v.x); o[1] = f2bf(v.y); o[2] = f2bf(v.z); o[3] = f2bf(v.w);
    *(u16x4*)(out + i) = o;
}

// ---------------- RoPE/xPos tables ----------------
__global__ __launch_bounds__(256) void rope_tables(float* __restrict__ ct,
                                                   float* __restrict__ st,
                                                   float* __restrict__ sc) {
    int idx = blockIdx.x * 256 + threadIdx.x;
    if (idx >= kT * 32) return;
    int t = idx >> 5, i = idx & 31;
    float half = 2.0f * (float)i;
    float inv_freq = powf(10000.0f, -half / 64.0f);
    float fr = (float)t * inv_freq;
    float sv = (half + 0.4f * 64.0f) / (1.4f * 64.0f);
    float p = ((float)t - 1024.0f) / 512.0f;
    ct[idx] = cosf(fr);
    st[idx] = sinf(fr);
    sc[idx] = powf(sv, p);
}

// ---------------- bf16 MFMA GEMM: C[M,N] = A[M,K] * Bm[N,K]^T, fp32 out ----------
// tile 128 x TN, BK=64, 4 waves (2x2). global_load_lds staging with pre-swizzled
// global source; LDS reads XOR-swizzled -> conflict-free ds_read_b128.
template <int TN>
__global__ __launch_bounds__(256) void gemm_bt(const unsigned short* __restrict__ A,
                                               const unsigned short* __restrict__ Bm,
                                               float* __restrict__ Cm,
                                               int N, int K) {
    constexpr int NF = TN / 32;          // col fragments per wave
    constexpr int CH = 16 + TN / 8;      // total 1KB staging chunks (A first)
    __shared__ unsigned short Al[128 * 64];
    __shared__ unsigned short Bl[TN * 64];
    char* ab = (char*)Al;
    char* bb = (char*)Bl;
    const int tid = threadIdx.x;
    const int l = tid & 63, w = tid >> 6;
    const int wr = w >> 1, wc = w & 1;
    const int tm = blockIdx.y * 128, tn = blockIdx.x * TN;
    const int ri = l >> 3;               // row within 8-row chunk
    const int su = (l & 7) ^ (ri & 7);   // pre-swizzled 16B unit within row

    f32x4 zero4 = {0.0f, 0.0f, 0.0f, 0.0f};
    f32x4 acc[4][NF];
#pragma unroll
    for (int m = 0; m < 4; m++)
#pragma unroll
        for (int n = 0; n < NF; n++) acc[m][n] = zero4;

    for (int kt = 0; kt < K; kt += 64) {
#pragma unroll
        for (int c = w; c < CH; c += 4) {
            if (c < 16) {
                const unsigned short* src = A + (size_t)(tm + c * 8 + ri) * K + kt + su * 8;
                GLDS16(src, ab + c * 1024);
            } else {
                int cb = c - 16;
                const unsigned short* src = Bm + (size_t)(tn + cb * 8 + ri) * K + kt + su * 8;
                GLDS16(src, bb + cb * 1024);
            }
        }
        __syncthreads();
#pragma unroll
        for (int ks = 0; ks < 2; ks++) {
            bf16x8 af[4], bfr[NF];
            int kbyte = ks * 64 + (l >> 4) * 16;
#pragma unroll
            for (int m = 0; m < 4; m++) {
                int row = wr * 64 + m * 16 + (l & 15);
                af[m] = *(const bf16x8*)(ab + row * 128 + (kbyte ^ ((row & 7) << 4)));
            }
#pragma unroll
            for (int n = 0; n < NF; n++) {
                int row = wc * (TN / 2) + n * 16 + (l & 15);
                bfr[n] = *(const bf16x8*)(bb + row * 128 + (kbyte ^ ((row & 7) << 4)));
            }
#pragma unroll
            for (int m = 0; m < 4; m++)
#pragma unroll
                for (int n = 0; n < NF; n++)
                    acc[m][n] = __builtin_amdgcn_mfma_f32_16x16x32_bf16(af[m], bfr[n], acc[m][n], 0, 0, 0);
        }
        __syncthreads();
    }
#pragma unroll
    for (int m = 0; m < 4; m++)
#pragma unroll
        for (int n = 0; n < NF; n++)
#pragma unroll
            for (int r = 0; r < 4; r++) {
                int row = tm + wr * 64 + m * 16 + (l >> 4) * 4 + r;
                int col = tn + wc * (TN / 2) + n * 16 + (l & 15);
                Cm[(size_t)row * N + col] = acc[m][n][r];
            }
}

// ---------------- RoPE q+k fused, with decay pre-scales folded in -------------
// src: fused qk GEMM out (B*T, 2048): q cols [0,1024), k cols [1024,2048)
// dq: q bf16 (B,H,T,D) scaled by 0.125 * gamma^(t mod 128)
// dk: k bf16 (B,H,T,D) scaled by gamma^(-(t mod 64))
// NOTE: exactly B*T*H*32 = 2^21 threads (each thread does BOTH q and k).
__global__ __launch_bounds__(256) void rope_qk(const float* __restrict__ src,
                                               const float* __restrict__ ct,
                                               const float* __restrict__ st,
                                               const float* __restrict__ sc,
                                               unsigned short* __restrict__ dq,
                                               unsigned short* __restrict__ dk) {
    int idx = blockIdx.x * 256 + threadIdx.x;  // B*T*H*32
    if (idx >= kB * kT * kH * 32) return;
    int i = idx & 31;
    int h = (idx >> 5) & 15;
    int t = (idx >> 9) & 2047;
    int b = idx >> 20;
    size_t row = (size_t)(b * kT + t) * 2048;
    float2 qv = *(const float2*)(src + row + h * kD + 2 * i);
    float2 kv = *(const float2*)(src + row + 1024 + h * kD + 2 * i);
    int ti = t * 32 + i;
    float c = ct[ti], s = st[ti], sv = sc[ti];
    float log2g = log2f(1.0f - exp2f(-5.0f - (float)h));
    float qdec = 0.125f * exp2f(log2g * (float)(t & 127));
    float kdec = exp2f(-log2g * (float)(t & 63));
    float cq = c * sv, sq = s * sv;
    float ck = c / sv, sk = s / sv;
    float q0 = (qv.x * cq - qv.y * sq) * qdec;
    float q1 = (qv.y * cq + qv.x * sq) * qdec;
    float k0 = (kv.x * ck - kv.y * sk) * kdec;
    float k1 = (kv.y * ck + kv.x * sk) * kdec;
    size_t doff = (((size_t)(b * kH + h) * kT + t) * kD) + 2 * i;
    u16x2 oq, ok;
    oq[0] = f2bf(q0); oq[1] = f2bf(q1);
    ok[0] = f2bf(k0); ok[1] = f2bf(k1);
    *(u16x2*)(dq + doff) = oq;
    *(u16x2*)(dk + doff) = ok;
}

// ---------------- V: fp32 (B*T, C) -> bf16 transposed (B,H,D,T) ----------------
__global__ __launch_bounds__(256) void vt_from_f32(const float* __restrict__ vf,
                                                   unsigned short* __restrict__ vtb) {
    __shared__ unsigned short tile[64][72];
    int tt = blockIdx.x * 64;
    int bh = blockIdx.y;
    int b = bh >> 4, h = bh & 15;
    int r = threadIdx.x >> 2;
    int cu = (threadIdx.x & 3) * 16;
    const float* srow = vf + ((size_t)(b * kT) + tt + r) * kC + h * kD + cu;
#pragma unroll
    for (int j = 0; j < 16; j += 4) {
        float4 v = *(const float4*)(srow + j);
        tile[r][cu + j + 0] = f2bf(v.x);
        tile[r][cu + j + 1] = f2bf(v.y);
        tile[r][cu + j + 2] = f2bf(v.z);
        tile[r][cu + j + 3] = f2bf(v.w);
    }
    __syncthreads();
    int d = threadIdx.x >> 2;
    int tb = (threadIdx.x & 3) * 16;
    bf16x8 o0, o1;
#pragma unroll
    for (int e = 0; e < 8; e++) {
        o0[e] = (short)tile[tb + e][d];
        o1[e] = (short)tile[tb + 8 + e][d];
    }
    unsigned short* drow = vtb + ((size_t)bh * kD + d) * kT + tt + tb;
    *(bf16x8*)(drow) = o0;
    *(bf16x8*)(drow + 8) = o1;
}

// ---------------- retention attention ----------------
// grid (8, 32): blockIdx.x = pair index (q-tiles bx and 15-bx), blockIdx.y = bh.
// 512 threads = 8 waves; each wave owns 16 q-rows of the 128-row q-tile.
// q pre-scaled by 0.125*g^(t&127), k by g^(-(s&63)); per-s-tile scalar g^(t0-s0).
__global__ __launch_bounds__(512) void retention_attn(const unsigned short* __restrict__ qb,
                                                      const unsigned short* __restrict__ kb,
                                                      const unsigned short* __restrict__ vtb,
                                                      float* __restrict__ y) {
    __shared__ unsigned short Kl[64 * 64];
    __shared__ unsigned short Vl[64 * 64];
    __shared__ unsigned short Pl[8 * 16 * 64];
    char* kbp = (char*)Kl;
    char* vbp = (char*)Vl;
    const int tid = threadIdx.x, l = tid & 63, w = tid >> 6;
    const int bh = blockIdx.y, h = bh & 15;
    const float log2g = log2f(1.0f - exp2f(-5.0f - (float)h));
    char* pw = ((char*)Pl) + w * 2048;
    const int ri = l >> 3;
    const int su = (l & 7) ^ (ri & 7);
    f32x4 zero4 = {0.0f, 0.0f, 0.0f, 0.0f};

#pragma unroll
    for (int half = 0; half < 2; ++half) {
        const int qt = half ? (15 - blockIdx.x) : blockIdx.x;
        const int t0 = qt * 128;
        bf16x8 aq[2];
        {
            const unsigned short* qrow = qb + (((size_t)bh * kT) + t0 + w * 16 + (l & 15)) * kD + (l >> 4) * 8;
            aq[0] = *(const bf16x8*)(qrow);
            aq[1] = *(const bf16x8*)(qrow + 32);
        }
        f32x4 accy[4];
#pragma unroll
        for (int j = 0; j < 4; j++) accy[j] = zero4;

        const int nst = 2 * qt + 2;
        for (int st = 0; st < nst; ++st) {
            const int s0 = st * 64;
            // stage K (chunks 0..7) and V^T (chunks 8..15); wave w does 2 chunks
#pragma unroll
            for (int j = 0; j < 2; ++j) {
                int c = w * 2 + j;
                if (c < 8) {
                    const unsigned short* src = kb + (((size_t)bh * kT) + s0 + c * 8 + ri) * kD + su * 8;
                    GLDS16(src, kbp + c * 1024);
                } else {
                    int cv = c - 8;
                    const unsigned short* src = vtb + (((size_t)bh * kD) + cv * 8 + ri) * kT + s0 + su * 8;
                    GLDS16(src, vbp + cv * 1024);
                }
            }
            __syncthreads();

            // S = Q K^T  (16 rows x 64 cols per wave)
            f32x4 sacc[4];
#pragma unroll
            for (int cb = 0; cb < 4; cb++) sacc[cb] = zero4;
#pragma unroll
            for (int ks = 0; ks < 2; ks++) {
                int kbyte = ks * 64 + (l >> 4) * 16;
#pragma unroll
                for (int cb = 0; cb < 4; cb++) {
                    int row = cb * 16 + (l & 15);
                    bf16x8 bk = *(const bf16x8*)(kbp + row * 128 + (kbyte ^ ((row & 7) << 4)));
                    sacc[cb] = __builtin_amdgcn_mfma_f32_16x16x32_bf16(aq[ks], bk, sacc[cb], 0, 0, 0);
                }
            }
            // P = S * g^(t0-s0), causal mask on diagonal tiles only
            const float ts = exp2f(log2g * (float)(t0 - s0));
            const bool diag = (st >= 2 * qt);
#pragma unroll
            for (int cb = 0; cb < 4; cb++) {
#pragma unroll
                for (int r = 0; r < 4; r++) {
                    int prow = (l >> 4) * 4 + r;
                    float p = sacc[cb][r] * ts;
                    if (diag) {
                        int rowt = t0 + w * 16 + prow;
                        int sg = s0 + cb * 16 + (l & 15);
                        p = (rowt >= sg) ? p : 0.0f;
                    }
                    int sl = cb * 16 + (l & 15);
                    *(unsigned short*)(pw + prow * 128 + ((sl * 2) ^ ((prow & 7) << 4))) = f2bf(p);
                }
            }
            // O += P V
#pragma unroll
            for (int ks = 0; ks < 2; ks++) {
                int kbyte = ks * 64 + (l >> 4) * 16;
                int prow = l & 15;
                bf16x8 ap = *(const bf16x8*)(pw + prow * 128 + (kbyte ^ ((prow & 7) << 4)));
#pragma unroll
                for (int jb = 0; jb < 4; jb++) {
                    int drow = jb * 16 + (l & 15);
                    bf16x8 bv = *(const bf16x8*)(vbp + drow * 128 + (kbyte ^ ((drow & 7) << 4)));
                    accy[jb] = __builtin_amdgcn_mfma_f32_16x16x32_bf16(ap, bv, accy[jb], 0, 0, 0);
                }
            }
            __syncthreads();
        }
#pragma unroll
        for (int jb = 0; jb < 4; jb++)
#pragma unroll
            for (int r = 0; r < 4; r++) {
                int row = t0 + w * 16 + (l >> 4) * 4 + r;
                int col = jb * 16 + (l & 15);
                y[(((size_t)bh * kT) + row) * kD + col] = accy[jb][r];
            }
    }
}

// ---------------- GroupNorm stats: two-stage ----------------
__global__ __launch_bounds__(256) void gn_part(const float* __restrict__ y,
                                               float* __restrict__ part) {
    int bh = blockIdx.y, seg = blockIdx.x;
    const float4* p = (const float4*)(y + (size_t)bh * (kT * kD) + (size_t)seg * (kT * kD / 8));
    float s = 0.0f, s2 = 0.0f;
    for (int i = threadIdx.x; i < (kT * kD / 8) / 4; i += 256) {
        float4 v = p[i];
        s += v.x + v.y + v.z + v.w;
        s2 += v.x * v.x + v.y * v.y + v.z * v.z + v.w * v.w;
    }
#pragma unroll
    for (int o = 32; o > 0; o >>= 1) {
        s += __shfl_down(s, o);
        s2 += __shfl_down(s2, o);
    }
    __shared__ float red[8];
    int tid = threadIdx.x;
    if ((tid & 63) == 0) {
        red[(tid >> 6) * 2] = s;
        red[(tid >> 6) * 2 + 1] = s2;
    }
    __syncthreads();
    if (tid == 0) {
        float S = 0.0f, S2 = 0.0f;
#pragma unroll
        for (int i = 0; i < 4; i++) { S += red[2 * i]; S2 += red[2 * i + 1]; }
        part[(bh * 8 + seg) * 2] = S;
        part[(bh * 8 + seg) * 2 + 1] = S2;
    }
}

__global__ __launch_bounds__(64) void gn_fin(const float* __restrict__ part,
                                             float* __restrict__ stats) {
    int bh = threadIdx.x;
    if (bh >= kB * kH) return;
    float S = 0.0f, S2 = 0.0f;
#pragma unroll
    for (int i = 0; i < 8; i++) {
        S += part[(bh * 8 + i) * 2];
        S2 += part[(bh * 8 + i) * 2 + 1];
    }
    const float inv = 1.0f / (float)(kT * kD);
    float mean = S * inv;
    float var = S2 * inv - mean * mean;
    stats[2 * bh] = mean;
    stats[2 * bh + 1] = rsqrtf(var + 1e-5f);
}

// ---------------- z = bf16( silu(g) * ((y - mean)*rstd*gw + gb) ) ----------------
__global__ __launch_bounds__(256) void fuse_z(const float* __restrict__ g,
                                              const float* __restrict__ y,
                                              const float* __restrict__ stats,
                                              const float* __restrict__ gnw,
                                              const float* __restrict__ gnb,
                                              unsigned short* __restrict__ z) {
    int idx = blockIdx.x * 256 + threadIdx.x;  // (B*T*C)/4
    int row = idx >> 8;
    int c = (idx & 255) << 2;
    int b = row >> 11, t = row & 2047;
    int h = c >> 6, d = c & 63;
    int bh = b * kH + h;
    float4 gv = *(const float4*)(g + (size_t)row * kC + c);
    float4 yv = *(const float4*)(y + (((size_t)bh * kT) + t) * kD + d);
    float mean = stats[2 * bh], rstd = stats[2 * bh + 1];
    float4 wv = *(const float4*)(gnw + c);
    float4 bv = *(const float4*)(gnb + c);
    float s0 = gv.x / (1.0f + expf(-gv.x));
    float s1 = gv.y / (1.0f + expf(-gv.y));
    float s2 = gv.z / (1.0f + expf(-gv.z));
    float s3 = gv.w / (1.0f + expf(-gv.w));
    u16x4 o;
    o[0] = f2bf(s0 * ((yv.x - mean) * rstd * wv.x + bv.x));
    o[1] = f2bf(s1 * ((yv.y - mean) * rstd * wv.y + bv.y));
    o[2] = f2bf(s2 * ((yv.z - mean) * rstd * wv.z + bv.z));
    o[3] = f2bf(s3 * ((yv.w - mean) * rstd * wv.w + bv.w));
    *(u16x4*)(z + (size_t)row * kC + c) = o;
}

extern "C" void kernel_launch(void* const* d_in, const int* in_sizes, int n_in,
                              void* d_out, int out_size, void* d_ws, size_t ws_size,
                              hipStream_t stream) {
    const float* x = (const float*)d_in[0];
    const float* w_qkv = (const float*)d_in[1];
    const float* w_gated = (const float*)d_in[2];
    const float* w_proj = (const float*)d_in[3];
    const float* gnw = (const float*)d_in[4];
    const float* gnb = (const float*)d_in[5];
    float* out = (float*)d_out;
    char* ws = (char*)d_ws;

    unsigned short* xb      = (unsigned short*)(ws + 0);         // 8 MB
    unsigned short* wqkvb   = (unsigned short*)(ws + 8388608);   // 6 MB
    unsigned short* wgatedb = (unsigned short*)(ws + 14680064);  // 2 MB
    unsigned short* wprojb  = (unsigned short*)(ws + 16777216);  // 2 MB
    unsigned short* qb      = (unsigned short*)(ws + 18874368);  // 8 MB (B,H,T,D) pre-scaled
    unsigned short* kbuf    = (unsigned short*)(ws + 27262976);  // 8 MB (B,H,T,D) pre-scaled
    unsigned short* vtb     = (unsigned short*)(ws + 35651584);  // 8 MB (B,H,D,T)
    unsigned short* zb      = (unsigned short*)(ws + 44040192);  // 8 MB
    float* cosT  = (float*)(ws + 52428800);                      // 256 KB
    float* sinT  = (float*)(ws + 52690944);                      // 256 KB
    float* sclT  = (float*)(ws + 52953088);                      // 256 KB
    float* stats = (float*)(ws + 53215232);                      // 256 B
    float* tmp0  = (float*)(ws + 53215488);                      // 32 MB: qk fp32 -> (y | g)
    float* tmpY  = tmp0;                                         // 16 MB: v fp32, then y
    float* tmpG  = tmp0 + 4194304;                               // 16 MB: g fp32
    // gn partials parked in zb region (free until fuse_z writes it)
    float* part  = (float*)(ws + 44040192);

    cvt_bf16<<<4096, 256, 0, stream>>>(x, xb, kB * kT * kC);
    cvt_bf16<<<3072, 256, 0, stream>>>(w_qkv, wqkvb, 3 * kC * kC);
    cvt_bf16<<<1024, 256, 0, stream>>>(w_gated, wgatedb, kC * kC);
    cvt_bf16<<<1024, 256, 0, stream>>>(w_proj, wprojb, kC * kC);
    rope_tables<<<256, 256, 0, stream>>>(cosT, sinT, sclT);

    // fused q|k GEMM: (4096 x 2048) = x @ [wq; wk]^T
    gemm_bt<128><<<dim3(2048 / 128, 4096 / 128), 256, 0, stream>>>(xb, wqkvb, tmp0, 2048, kC);
    rope_qk<<<8192, 256, 0, stream>>>(tmp0, cosT, sinT, sclT, qb, kbuf);

    // v GEMM -> fp32 (reuses tmp0 low half), then transpose to (B,H,D,T)
    gemm_bt<64><<<dim3(kC / 64, 4096 / 128), 256, 0, stream>>>(xb, wqkvb + (size_t)2 * kC * kC, tmpY, kC, kC);
    vt_from_f32<<<dim3(kT / 64, kB * kH), 256, 0, stream>>>(tmpY, vtb);

    // retention attention -> y fp32 (B,H,T,D) into tmpY (v fp32 dead after vt)
    retention_attn<<<dim3(8, kB * kH), 512, 0, stream>>>(qb, kbuf, vtb, tmpY);

    gn_part<<<dim3(8, kB * kH), 256, 0, stream>>>(tmpY, part);
    gn_fin<<<1, 64, 0, stream>>>(part, stats);

    // gated branch
    gemm_bt<64><<<dim3(kC / 64, 4096 / 128), 256, 0, stream>>>(xb, wgatedb, tmpG, kC, kC);
    fuse_z<<<4096, 256, 0, stream>>>(tmpG, tmpY, stats, gnw, gnb, zb);

    // proj -> out
    gemm_bt<64><<<dim3(kC / 64, 4096 / 128), 256, 0, stream>>>(zb, wprojb, out, kC, kC);
}